// Round 5
// baseline (333.946 us; speedup 1.0000x reference)
//
#include <hip/hip_runtime.h>

#define EPS_K 1e-7f

typedef __attribute__((ext_vector_type(8)))  short          frag8;  // 8 bf16
typedef __attribute__((ext_vector_type(16))) float          accf16; // MFMA C/D
typedef __attribute__((ext_vector_type(4)))  unsigned short us4;    // 8B read
typedef __attribute__((ext_vector_type(4)))  float          f32x4;

__device__ __forceinline__ unsigned f2bf(float f) {
  union { float f; unsigned u; } v; v.f = f;
  unsigned u = v.u;
  u += 0x7FFFu + ((u >> 16) & 1u);   // RNE
  return u >> 16;
}
__device__ __forceinline__ float bf2f(unsigned short s) {
  union { unsigned u; float f; } v; v.u = ((unsigned)s) << 16;
  return v.f;
}
__device__ __forceinline__ float rcp_f(float x) {
  return __builtin_amdgcn_rcpf(x);   // validated rounds 3/4: absmax unchanged
}

// ---------------------------------------------------------------------------
// Pre-pass: W (2048,32,32) f32 [s][t][u] -> Wbf bf16 [s][u][t] (4 MB in ws)
// (verified, unchanged since round 0)
// ---------------------------------------------------------------------------
__global__ __launch_bounds__(256) void wbf_prep(
    const float* __restrict__ Wt, unsigned short* __restrict__ Wbf)
{
  __shared__ unsigned short tile[32 * 33];
  const int s   = blockIdx.x;
  const int tid = threadIdx.x;
  {
    const int t  = tid >> 3;
    const int uc = tid & 7;
    const float4 v = *(const float4*)(Wt + s * 1024 + t * 32 + 4 * uc);
    tile[t * 33 + 4 * uc + 0] = (unsigned short)f2bf(v.x);
    tile[t * 33 + 4 * uc + 1] = (unsigned short)f2bf(v.y);
    tile[t * 33 + 4 * uc + 2] = (unsigned short)f2bf(v.z);
    tile[t * 33 + 4 * uc + 3] = (unsigned short)f2bf(v.w);
  }
  __syncthreads();
  {
    const int u  = tid >> 3;
    const int tc = tid & 7;
    uint2 d;
    d.x = (unsigned)tile[(4 * tc + 0) * 33 + u] | ((unsigned)tile[(4 * tc + 1) * 33 + u] << 16);
    d.y = (unsigned)tile[(4 * tc + 2) * 33 + u] | ((unsigned)tile[(4 * tc + 3) * 33 + u] << 16);
    *(uint2*)(Wbf + s * 1024 + u * 32 + 4 * tc) = d;
  }
}

// ---------------------------------------------------------------------------
// Pass 1: repack x = inp*msk (f32, [b][t][s]) -> Y (bf16, fragment layout).
//
// Y layout: quarter Q = bg*4+bq (b = bg*32+bq*8+b'), per (Q,s) a 512-B slice:
//   ushort offset within slice = c*64 + slot*8 + j,  where c = t>>3, j = t&7,
//   slot = b' ^ ((s>>2)&7)   (XOR swizzle -> LDS bank spread, 16-B frag units
//   preserved; pass 2 applies the same XOR to recover b').
//
// Every HBM access ≥512 B contiguous:
//   reads:  per wave-instr two 512-B runs (lanes = s axis, 128-s window)
//   writes: 64-KB contiguous block copy (LDS holds the transposed window)
// Grid 1024 = 64 Q x 16 s-windows; 512 thr (wave v = b'); LDS 64 KB,
// 2 blocks/CU.
// ---------------------------------------------------------------------------
__global__ __launch_bounds__(512, 4) void repack(
    const float* __restrict__ inp, const float* __restrict__ msk,
    unsigned short* __restrict__ Y)
{
  __shared__ unsigned short sl[32768];          // 128 s x 256 ushort = 64 KB
  const int tid  = threadIdx.x;
  const int lane = tid & 63;
  const int b7   = tid >> 6;                    // wave id = b' 0..7
  const int Q    = blockIdx.x & 63;             // bg*4+bq
  const int w    = blockIdx.x >> 6;             // s-window 0..15
  const int l5   = lane >> 5;                   // row parity (t)
  const int l31  = lane & 31;                   // s-quad index

  // global b = Q*8 + b7 = bg*32 + bq*8 + b'
  const size_t rbase = ((size_t)(Q * 8 + b7) * 32 + l5) * 2048 + w * 128 + 4 * l31;
  const int xb = (b7 ^ (lane & 7)) * 8;         // lane&7 == (s_loc>>2)&7 here

  #pragma unroll
  for (int p0 = 0; p0 < 16; p0 += 4) {
    f32x4 vi[4], vm[4];
    #pragma unroll
    for (int q = 0; q < 4; ++q) {
      const size_t off = rbase + (size_t)(2 * (p0 + q)) * 2048;
      vi[q] = *(const f32x4*)(inp + off);
      vm[q] = *(const f32x4*)(msk + off);
    }
    #pragma unroll
    for (int q = 0; q < 4; ++q) {
      const int t_ = 2 * (p0 + q) + l5;
      const int ab = (t_ >> 3) * 64 + (t_ & 7) + xb;
      #pragma unroll
      for (int k = 0; k < 4; ++k)
        sl[(4 * l31 + k) * 256 + ab] = (unsigned short)f2bf(vi[q][k] * vm[q][k]);
    }
  }
  __syncthreads();

  const size_t ybyte = ((size_t)Q * 2048 + (size_t)w * 128) * 512;
  #pragma unroll
  for (int i = 0; i < 8; ++i) {
    const int e = i * 512 + tid;                // 16-B chunk 0..4095
    const uint4 d = *(const uint4*)((const char*)sl + (size_t)e * 16);
    *(uint4*)((char*)Y + ybyte + (size_t)e * 16) = d;
  }
}

// ---------------------------------------------------------------------------
// Pass 2: compute. 1024 blocks (16 bg x 64 sg) x 256 thr (4 waves), each wave
// owns 8 s. No LDS staging, no barriers in the main loop — x/W/bias read
// directly from (mostly L3-resident) global in fragment order.
// MFMA C layout (HW-validated): col = lane&31 = b, row u = (r&3)+8*(r>>2)+4h.
// ---------------------------------------------------------------------------
__global__ __launch_bounds__(256, 4) void attn_comp(
    const unsigned short* __restrict__ Y,
    const unsigned short* __restrict__ Wbf,
    const float* __restrict__ bias,
    float* __restrict__ part)
{
  __shared__ float red[4096];                   // 16 KB epilogue scratch
  const int tid  = threadIdx.x;
  const int bg   = blockIdx.x & 15;
  const int sg   = blockIdx.x >> 4;             // 0..63
  const int lane = tid & 63;
  const int wv   = tid >> 6;
  const int n    = lane & 31;                   // b (B-frag col) / u (A-frag)
  const int h    = lane >> 5;

  const unsigned short* Yq = Y + ((size_t)(bg * 4 + (n >> 3)) * 2048) * 256;

  float O[16];
  #pragma unroll
  for (int r = 0; r < 16; ++r) O[r] = 0.f;

  #pragma unroll 2
  for (int it = 0; it < 8; ++it) {
    const int s = sg * 32 + wv * 8 + it;
    const unsigned short* slp = Yq + (size_t)s * 256;
    const int bt = (((n & 7) ^ ((s >> 2) & 7)) * 8);

    const frag8 b1 = *(const frag8*)(slp + h * 64 + bt);        // t=8h..8h+7
    const frag8 b2 = *(const frag8*)(slp + (h + 2) * 64 + bt);  // +16

    const unsigned short* wp = Wbf + (size_t)s * 1024 + n * 32 + 8 * h;
    const frag8 a1 = *(const frag8*)(wp);
    const frag8 a2 = *(const frag8*)(wp + 16);

    accf16 acc;
    #pragma unroll
    for (int g = 0; g < 4; ++g) {
      const f32x4 bb = *(const f32x4*)(bias + s * 32 + 8 * g + 4 * h);
      acc[4 * g + 0] = bb[0]; acc[4 * g + 1] = bb[1];
      acc[4 * g + 2] = bb[2]; acc[4 * g + 3] = bb[3];
    }
    acc = __builtin_amdgcn_mfma_f32_32x32x16_bf16(a1, b1, acc, 0, 0, 0);
    acc = __builtin_amdgcn_mfma_f32_32x32x16_bf16(a2, b2, acc, 0, 0, 0);

    // e = exp(tanh(z)); tanh(z) = 1 - 2/(exp(2z)+1)
    float ps = 0.f;
    #pragma unroll
    for (int r = 0; r < 16; ++r) {
      const float z  = acc[r];
      const float e2 = __expf(2.f * z);
      const float th = 1.f - 2.f * rcp_f(e2 + 1.f);
      acc[r] = __expf(th);
      ps    += acc[r];
    }
    const float tot = ps + __shfl_xor(ps, 32, 64);
    const float inv = rcp_f(tot + EPS_K);

    #pragma unroll
    for (int g = 0; g < 4; ++g) {
      const us4 xv = *(const us4*)(slp + g * 64 + bt + 4 * h);  // u=8g+4h+i
      #pragma unroll
      for (int i = 0; i < 4; ++i)
        O[4 * g + i] += acc[4 * g + i] * inv * bf2f(xv[i]);
    }
  }

  // ---- cross-wave reduction (verified round-0 code) ----
  #pragma unroll
  for (int r = 0; r < 16; ++r) {
    const int u = (r & 3) + 8 * (r >> 2) + 4 * h;
    red[wv * 1024 + n * 32 + (u ^ n)] = O[r];
  }
  __syncthreads();

  const int q0 = tid * 4;
  f32x4 v;
  #pragma unroll
  for (int i = 0; i < 4; ++i) {
    const int q = q0 + i;
    const int b = q >> 5, u = q & 31;
    float sum = 0.f;
    #pragma unroll
    for (int w = 0; w < 4; ++w) sum += red[w * 1024 + b * 32 + (u ^ b)];
    v[i] = sum;
  }
  *(f32x4*)(part + (size_t)sg * 16384 + bg * 1024 + q0) = v;
}

// out[f] = sum over 64 s-groups of part[sg][f]
__global__ __launch_bounds__(256) void reduce_part(
    const float* __restrict__ part, float* __restrict__ out)
{
  const int f = blockIdx.x * 256 + threadIdx.x;
  float s = 0.f;
  #pragma unroll 8
  for (int sg = 0; sg < 64; ++sg) s += part[(size_t)sg * 16384 + f];
  out[f] = s;
}

// ---------------------------------------------------------------------------
// Safety fallback (ws too small): correct, slow, f32-precise.
// thread = (b, s-chunk of 64); atomicAdd partials into zeroed out.
// ---------------------------------------------------------------------------
__global__ __launch_bounds__(256) void attn_naive(
    const float* __restrict__ inp, const float* __restrict__ msk,
    const float* __restrict__ Wt, const float* __restrict__ bias,
    float* __restrict__ out)
{
  const int idx = blockIdx.x * 256 + threadIdx.x;  // 0..16383
  const int b = idx >> 5, sc = idx & 31;
  float O[32];
  #pragma unroll
  for (int u = 0; u < 32; ++u) O[u] = 0.f;
  for (int si = 0; si < 64; ++si) {
    const int s = sc * 64 + si;
    float x[32], z[32];
    for (int t = 0; t < 32; ++t) {
      x[t] = inp[((size_t)b * 32 + t) * 2048 + s] * msk[((size_t)b * 32 + t) * 2048 + s];
      z[t] = bias[s * 32 + t];
    }
    for (int t = 0; t < 32; ++t) {
      const float xv = x[t];
      for (int u = 0; u < 32; ++u) z[u] += xv * Wt[(size_t)s * 1024 + t * 32 + u];
    }
    float e[32], ps = 0.f;
    for (int u = 0; u < 32; ++u) { e[u] = expf(tanhf(z[u])); ps += e[u]; }
    const float inv = 1.f / (ps + EPS_K);
    for (int u = 0; u < 32; ++u) O[u] += e[u] * inv * x[u];
  }
  for (int u = 0; u < 32; ++u) atomicAdd(out + b * 32 + u, O[u]);
}

extern "C" void kernel_launch(void* const* d_in, const int* in_sizes, int n_in,
                              void* d_out, int out_size, void* d_ws, size_t ws_size,
                              hipStream_t stream) {
  const float* inp  = (const float*)d_in[0];   // (512,32,2048) f32
  const float* msk  = (const float*)d_in[1];   // (512,32,2048) f32
  const float* Wt   = (const float*)d_in[2];   // (2048,32,32)  f32
  const float* bias = (const float*)d_in[3];   // (2048,32)     f32
  float* out = (float*)d_out;                  // (512,32)      f32

  const size_t part_sz = (size_t)64 * 16384 * sizeof(float);           // 4 MiB
  const size_t wbf_sz  = (size_t)2048 * 1024 * sizeof(unsigned short); // 4 MiB
  const size_t y_sz    = (size_t)512 * 32 * 2048 * sizeof(unsigned short); // 64 MiB

  if (ws_size >= part_sz + wbf_sz + y_sz) {
    float* part = (float*)d_ws;
    unsigned short* Wbf = (unsigned short*)((char*)d_ws + part_sz);
    unsigned short* Y   = (unsigned short*)((char*)d_ws + part_sz + wbf_sz);
    repack<<<dim3(1024), dim3(512), 0, stream>>>(inp, msk, Y);
    wbf_prep<<<dim3(2048), dim3(256), 0, stream>>>(Wt, Wbf);
    attn_comp<<<dim3(1024), dim3(256), 0, stream>>>(Y, Wbf, bias, part);
    reduce_part<<<dim3(64), dim3(256), 0, stream>>>(part, out);
  } else {
    (void)hipMemsetAsync(out, 0, (size_t)out_size * sizeof(float), stream);
    attn_naive<<<dim3(64), dim3(256), 0, stream>>>(inp, msk, Wt, bias, out);
  }
}